// Round 2
// 185.934 us; speedup vs baseline: 1.0309x; 1.0309x over previous
//
#include <hip/hip_runtime.h>
#include <hip/hip_fp16.h>

#define NN 100000
#define NE 1600000

typedef short s8v  __attribute__((ext_vector_type(8)));    // 8 bf16 = 4 VGPRs
typedef float f4   __attribute__((ext_vector_type(4)));
typedef float f16v __attribute__((ext_vector_type(16)));   // 32x32 MFMA accumulator

// ---------- dtype helpers ----------
__device__ __forceinline__ unsigned short f2b(float f) {   // fp32 -> bf16 RNE (prep only)
    unsigned int u = __float_as_uint(f);
    return (unsigned short)((u + 0x7fffu + ((u >> 16) & 1u)) >> 16);
}
__device__ __forceinline__ unsigned int cvtpk(float lo, float hi) {  // 2xf32 -> packed bf16 (RNE)
    unsigned int r;
    asm("v_cvt_pk_bf16_f32 %0, %1, %2" : "=v"(r) : "v"(lo), "v"(hi));
    return r;
}

// Inter-layer exchange for 32x32x16 chains.
// C regs BASE..BASE+7 hold rows {0..3, 8..11} + 4*h5 (relative to a 16-row K-chunk).
// Next-layer B-frag needs lane(l,h5), elem j -> row 8*h5 + j of this chunk.
// v_permlane32_swap_b32 vdst, vsrc : vdst[32:63] <-> vsrc[0:31]; builtin returns {vdst', vsrc'}.
// swap(a, b):  r[0] = {lo: own a | hi: partner-lo b}   -> j = 0..1 word
//              r[1] = {lo: partner-hi a | hi: own b}   -> j = 4..5 word
template<int BASE>
__device__ __forceinline__ s8v interleave8(f16v C) {
    unsigned a0 = cvtpk(fmaxf(C[BASE + 0], 0.f), fmaxf(C[BASE + 1], 0.f)); // rel rows 0,1 (+4h5)
    unsigned a1 = cvtpk(fmaxf(C[BASE + 2], 0.f), fmaxf(C[BASE + 3], 0.f)); // rel rows 2,3
    unsigned b0 = cvtpk(fmaxf(C[BASE + 4], 0.f), fmaxf(C[BASE + 5], 0.f)); // rel rows 8,9
    unsigned b1 = cvtpk(fmaxf(C[BASE + 6], 0.f), fmaxf(C[BASE + 7], 0.f)); // rel rows 10,11
    auto r0 = __builtin_amdgcn_permlane32_swap((int)a0, (int)b0, false, false);
    auto r1 = __builtin_amdgcn_permlane32_swap((int)a1, (int)b1, false, false);
    uint4 q;
    q.x = (unsigned)r0[0];   // j0,1 : lo lane = rows 0,1  | hi lane = rows 8,9
    q.y = (unsigned)r1[0];   // j2,3 : lo lane = rows 2,3  | hi lane = rows 10,11
    q.z = (unsigned)r0[1];   // j4,5 : lo lane = rows 4,5  | hi lane = rows 12,13
    q.w = (unsigned)r1[1];   // j6,7 : lo lane = rows 6,7  | hi lane = rows 14,15
    return __builtin_bit_cast(s8v, q);
}

// ---------- workspace layout (float index) ----------
// pk@0 [50000 floats = 100000 __half2]  (x = msg sum, y = count; pk_add_f16 atomics)
// phi b1 @204868[64] | phi w2 @204932[64] | phi b2 @204996[1]
// phi fragW0 @205000 (2048 bf16: [t*2+s][lane][8])  | phi fragW1 @206024 (4096 bf16: [t*4+s2][lane][8])
// flags @208100 (1 int)
// gam fragW0 @208104 (1024 bf16: [t][lane][8])      | gam fragW1 @209128 (4096 bf16)
// gam b1 @211176[64] | gam w2 @211240[64] | gam b2 @211304[1]
// 32x32x16 A-frag mapping: lane l, elem j -> A[row = 32*t + (l&31)][k = 16*s + 8*(l>>5) + j]

__global__ __launch_bounds__(256) void prep(
    const float* __restrict__ pW0, const float* __restrict__ pb0,
    const float* __restrict__ pW1, const float* __restrict__ pb1,
    const float* __restrict__ pW2, const float* __restrict__ pb2,
    const float* __restrict__ gW0, const float* __restrict__ gb0,
    const float* __restrict__ gW1, const float* __restrict__ gb1,
    const float* __restrict__ gW2, const float* __restrict__ gb2,
    const int* __restrict__ ei, float* __restrict__ ws)
{
    // ---- zero the pk accumulator (all blocks) ----
    for (int i = blockIdx.x * 256 + threadIdx.x; i < 50000; i += gridDim.x * 256)
        ws[i] = 0.0f;

    // ---- sniff edge-index width (last block only) ----
    if (blockIdx.x == gridDim.x - 1) {
        __shared__ int s_zero;
        if (threadIdx.x == 0) s_zero = 0;
        __syncthreads();
        int zero = 0;
        for (int i = threadIdx.x; i < 1024; i += 256)
            if (ei[2 * i + 1] == 0) zero++;      // int64 high words all zero
        atomicAdd(&s_zero, zero);
        __syncthreads();
        if (threadIdx.x == 0) ((int*)(ws + 208100))[0] = (s_zero > 512) ? 1 : 0;
        return;
    }

    // ---- weight staging ----
    int t = blockIdx.x * 256 + threadIdx.x;
    if (t < 64)        ws[204868 + t] = pb1[t];
    else if (t < 128)  ws[204932 + t - 64] = pW2[t - 64];
    else if (t == 128) ws[204996] = pb2[0];
    else if (t >= 256 && t < 2304) {            // phi fragW0 (2048): bias folded at k=18
        int fe = t - 256;
        int j = fe & 7, ln = (fe >> 3) & 63, ts = fe >> 9;   // ts = tt*2+s
        int tt = ts >> 1, s = ts & 1;
        int k = s * 16 + (ln >> 5) * 8 + j;
        int n = tt * 32 + (ln & 31);
        float v = (k < 18) ? pW0[k * 64 + n] : ((k == 18) ? pb0[n] : 0.0f);
        ((unsigned short*)(ws + 205000))[fe] = f2b(v);
    }
    else if (t >= 2304 && t < 6400) {           // phi fragW1 (4096)
        int fe = t - 2304;
        int j = fe & 7, ln = (fe >> 3) & 63, f = fe >> 9;    // f = tt*4+s2
        int tt = f >> 2, s2 = f & 3;
        int k = s2 * 16 + (ln >> 5) * 8 + j;
        int n = tt * 32 + (ln & 31);
        ((unsigned short*)(ws + 206024))[fe] = f2b(pW1[k * 64 + n]);
    }
    else if (t >= 6400 && t < 7424) {           // gam fragW0 (1024): bias folded at k=9
        int fe = t - 6400;
        int j = fe & 7, ln = (fe >> 3) & 63, tt = fe >> 9;
        int k = (ln >> 5) * 8 + j;
        int n = tt * 32 + (ln & 31);
        float v = (k < 9) ? gW0[k * 64 + n] : ((k == 9) ? gb0[n] : 0.0f);
        ((unsigned short*)(ws + 208104))[fe] = f2b(v);
    }
    else if (t >= 7424 && t < 11520) {          // gam fragW1 (4096)
        int fe = t - 7424;
        int j = fe & 7, ln = (fe >> 3) & 63, f = fe >> 9;
        int tt = f >> 2, s2 = f & 3;
        int k = s2 * 16 + (ln >> 5) * 8 + j;
        int n = tt * 32 + (ln & 31);
        ((unsigned short*)(ws + 209128))[fe] = f2b(gW1[k * 64 + n]);
    }
    else if (t >= 11520 && t < 11584) ws[211176 + t - 11520] = gb1[t - 11520];
    else if (t >= 11584 && t < 11648) ws[211240 + t - 11584] = gW2[t - 11584];
    else if (t == 11648) ws[211304] = gb2[0];
}

// ---------- edge kernel: phi as 32x32x16 MFMA, 32 edges/wave, permlane exchange ----------
__global__ __launch_bounds__(256) void edge_mfma(
    const float* __restrict__ x, const float* __restrict__ pos,
    const int* __restrict__ ei, float* __restrict__ ws,
    const int* __restrict__ flags)
{
    const int lane = threadIdx.x & 63;
    const int c5   = lane & 31;
    const int h5   = lane >> 5;
    const int fidx = flags[0];

    const unsigned short* fw0 = (const unsigned short*)(ws + 205000);
    const unsigned short* fw1 = (const unsigned short*)(ws + 206024);
    s8v wA0[4], wA1[8];
#pragma unroll
    for (int t = 0; t < 4; t++) wA0[t] = *(const s8v*)(fw0 + (t * 64 + lane) * 8);
#pragma unroll
    for (int f = 0; f < 8; f++) wA1[f] = *(const s8v*)(fw1 + (f * 64 + lane) * 8);

    // bias (as layer-2 accumulator init) and w2, row = 32*t + 8*g + 4*h5 + i
    const float* b1p = ws + 204868;
    const float* w2p = ws + 204932;
    f16v B1a, B1b;
    f4 w2v[8];
#pragma unroll
    for (int g = 0; g < 4; g++) {
        f4 ba = *(const f4*)(b1p + g * 8 + h5 * 4);
        f4 bb = *(const f4*)(b1p + 32 + g * 8 + h5 * 4);
#pragma unroll
        for (int i = 0; i < 4; i++) { B1a[g * 4 + i] = ba[i]; B1b[g * 4 + i] = bb[i]; }
        w2v[g]     = *(const f4*)(w2p + g * 8 + h5 * 4);
        w2v[4 + g] = *(const f4*)(w2p + 32 + g * 8 + h5 * 4);
    }
    const float phib2 = ws[204996];

    f16v zz;
#pragma unroll
    for (int r = 0; r < 16; r++) zz[r] = 0.f;

    __half2* pk = (__half2*)ws;
    const float2* pf = (const float2*)pos;

    const int gw    = blockIdx.x * 4 + (threadIdx.x >> 6);
    const int nwave = gridDim.x * 4;

    for (int tile = gw; tile < NE / 32; tile += nwave) {
        int eg = tile * 32 + c5;
        int src, dst;
        if (fidx) { src = ei[2 * eg]; dst = ei[2 * (NE + eg)]; }
        else      { src = ei[eg];     dst = ei[NE + eg]; }
        if ((unsigned)src >= (unsigned)NN) src = 0;
        if ((unsigned)dst >= (unsigned)NN) dst = 0;

        // half-wave role split: h5=0 -> x[dst] (k=0..7) + pos; h5=1 -> x[src] (k=8..15)
        int sel = h5 ? src : dst;
        f4 xa = *(const f4*)(x + sel * 8);
        f4 xb = *(const f4*)(x + sel * 8 + 4);
        float dpx = 0.f, dpy = 0.f, onev = 0.f;
        if (!h5) {
            float2 ps = pf[src], pd = pf[dst];
            dpx = ps.x - pd.x; dpy = ps.y - pd.y; onev = 1.0f;
        }
        uint4 q0;
        q0.x = cvtpk(xa[0], xa[1]); q0.y = cvtpk(xa[2], xa[3]);
        q0.z = cvtpk(xb[0], xb[1]); q0.w = cvtpk(xb[2], xb[3]);
        s8v bf0 = __builtin_bit_cast(s8v, q0);
        uint4 q1;                               // chunk1: k=16,17 dpos, k=18 bias; h5=1 side is zero (A is zero there)
        q1.x = cvtpk(dpx, dpy); q1.y = cvtpk(onev, 0.f); q1.z = 0u; q1.w = 0u;
        s8v bf1 = __builtin_bit_cast(s8v, q1);

        // layer 1: two 32-row tiles, K = 2x16
        f16v C1 = __builtin_amdgcn_mfma_f32_32x32x16_bf16(wA0[0], bf0, zz, 0, 0, 0);
        C1 = __builtin_amdgcn_mfma_f32_32x32x16_bf16(wA0[1], bf1, C1, 0, 0, 0);
        s8v g0 = interleave8<0>(C1);            // h1 rows  0..15
        s8v g1 = interleave8<8>(C1);            // h1 rows 16..31
        C1 = __builtin_amdgcn_mfma_f32_32x32x16_bf16(wA0[2], bf0, zz, 0, 0, 0);
        C1 = __builtin_amdgcn_mfma_f32_32x32x16_bf16(wA0[3], bf1, C1, 0, 0, 0);
        s8v g2 = interleave8<0>(C1);            // h1 rows 32..47
        s8v g3 = interleave8<8>(C1);            // h1 rows 48..63

        // layer 2: K=64 = 4x16, accumulator starts at b1
        f16v C2a = __builtin_amdgcn_mfma_f32_32x32x16_bf16(wA1[0], g0, B1a, 0, 0, 0);
        C2a = __builtin_amdgcn_mfma_f32_32x32x16_bf16(wA1[1], g1, C2a, 0, 0, 0);
        C2a = __builtin_amdgcn_mfma_f32_32x32x16_bf16(wA1[2], g2, C2a, 0, 0, 0);
        C2a = __builtin_amdgcn_mfma_f32_32x32x16_bf16(wA1[3], g3, C2a, 0, 0, 0);
        f16v C2b = __builtin_amdgcn_mfma_f32_32x32x16_bf16(wA1[4], g0, B1b, 0, 0, 0);
        C2b = __builtin_amdgcn_mfma_f32_32x32x16_bf16(wA1[5], g1, C2b, 0, 0, 0);
        C2b = __builtin_amdgcn_mfma_f32_32x32x16_bf16(wA1[6], g2, C2b, 0, 0, 0);
        C2b = __builtin_amdgcn_mfma_f32_32x32x16_bf16(wA1[7], g3, C2b, 0, 0, 0);

        float pm = 0.f;
#pragma unroll
        for (int r = 0; r < 16; r++) {
            pm = fmaf(fmaxf(C2a[r], 0.f), w2v[r >> 2][r & 3], pm);
            pm = fmaf(fmaxf(C2b[r], 0.f), w2v[4 + (r >> 2)][r & 3], pm);
        }
        // cross-half sum: one self-swap (order-insensitive)
        int pi = __builtin_bit_cast(int, pm);
        auto rr = __builtin_amdgcn_permlane32_swap(pi, pi, false, false);
        float msg = __builtin_bit_cast(float, (int)rr[0])
                  + __builtin_bit_cast(float, (int)rr[1]) + phib2;

        if (!h5)      // one packed atomic per edge: (msg, 1.0)
            unsafeAtomicAdd(pk + dst, __halves2half2(__float2half(msg), __float2half(1.0f)));
    }
}

// ---------- node kernel: gamma as 32x32x16 MFMA, 32 nodes/wave, no atomics ----------
__global__ __launch_bounds__(256) void node_mfma(
    const float* __restrict__ x, float* __restrict__ ws,
    float* __restrict__ out)
{
    const int lane = threadIdx.x & 63;
    const int c5   = lane & 31;
    const int h5   = lane >> 5;

    const unsigned short* fw0 = (const unsigned short*)(ws + 208104);
    const unsigned short* fw1 = (const unsigned short*)(ws + 209128);
    s8v wA0[2], wA1[8];
#pragma unroll
    for (int t = 0; t < 2; t++) wA0[t] = *(const s8v*)(fw0 + (t * 64 + lane) * 8);
#pragma unroll
    for (int f = 0; f < 8; f++) wA1[f] = *(const s8v*)(fw1 + (f * 64 + lane) * 8);

    const float* b1p = ws + 211176;
    const float* w2p = ws + 211240;
    f16v B1a, B1b;
    f4 w2v[8];
#pragma unroll
    for (int g = 0; g < 4; g++) {
        f4 ba = *(const f4*)(b1p + g * 8 + h5 * 4);
        f4 bb = *(const f4*)(b1p + 32 + g * 8 + h5 * 4);
#pragma unroll
        for (int i = 0; i < 4; i++) { B1a[g * 4 + i] = ba[i]; B1b[g * 4 + i] = bb[i]; }
        w2v[g]     = *(const f4*)(w2p + g * 8 + h5 * 4);
        w2v[4 + g] = *(const f4*)(w2p + 32 + g * 8 + h5 * 4);
    }
    const float gamb2 = ws[211304];

    f16v zz;
#pragma unroll
    for (int r = 0; r < 16; r++) zz[r] = 0.f;

    const __half2* pk = (const __half2*)ws;

    const int gw    = blockIdx.x * 4 + (threadIdx.x >> 6);
    const int nwave = gridDim.x * 4;

    for (int tile = gw; tile < NN / 32; tile += nwave) {   // 3125 tiles, exact
        int n = tile * 32 + c5;
        f4 xa = {0.f, 0.f, 0.f, 0.f}, xb = {0.f, 0.f, 0.f, 0.f};
        float aggv = 0.f;
        if (!h5) {
            xa = *(const f4*)(x + n * 8);
            xb = *(const f4*)(x + n * 8 + 4);
        } else {
            __half2 pc = pk[n];
            aggv = __half2float(pc.x) / fmaxf(__half2float(pc.y), 1.0f);
        }
        uint4 q0;                               // h5=0: x (k=0..7); h5=1: k=8 agg, k=9 bias
        q0.x = h5 ? cvtpk(aggv, 1.0f) : cvtpk(xa[0], xa[1]);
        q0.y = h5 ? 0u : cvtpk(xa[2], xa[3]);
        q0.z = h5 ? 0u : cvtpk(xb[0], xb[1]);
        q0.w = h5 ? 0u : cvtpk(xb[2], xb[3]);
        s8v bf0 = __builtin_bit_cast(s8v, q0);

        f16v C1 = __builtin_amdgcn_mfma_f32_32x32x16_bf16(wA0[0], bf0, zz, 0, 0, 0);
        s8v g0 = interleave8<0>(C1);
        s8v g1 = interleave8<8>(C1);
        C1 = __builtin_amdgcn_mfma_f32_32x32x16_bf16(wA0[1], bf0, zz, 0, 0, 0);
        s8v g2 = interleave8<0>(C1);
        s8v g3 = interleave8<8>(C1);

        f16v C2a = __builtin_amdgcn_mfma_f32_32x32x16_bf16(wA1[0], g0, B1a, 0, 0, 0);
        C2a = __builtin_amdgcn_mfma_f32_32x32x16_bf16(wA1[1], g1, C2a, 0, 0, 0);
        C2a = __builtin_amdgcn_mfma_f32_32x32x16_bf16(wA1[2], g2, C2a, 0, 0, 0);
        C2a = __builtin_amdgcn_mfma_f32_32x32x16_bf16(wA1[3], g3, C2a, 0, 0, 0);
        f16v C2b = __builtin_amdgcn_mfma_f32_32x32x16_bf16(wA1[4], g0, B1b, 0, 0, 0);
        C2b = __builtin_amdgcn_mfma_f32_32x32x16_bf16(wA1[5], g1, C2b, 0, 0, 0);
        C2b = __builtin_amdgcn_mfma_f32_32x32x16_bf16(wA1[6], g2, C2b, 0, 0, 0);
        C2b = __builtin_amdgcn_mfma_f32_32x32x16_bf16(wA1[7], g3, C2b, 0, 0, 0);

        float pm = 0.f;
#pragma unroll
        for (int r = 0; r < 16; r++) {
            pm = fmaf(fmaxf(C2a[r], 0.f), w2v[r >> 2][r & 3], pm);
            pm = fmaf(fmaxf(C2b[r], 0.f), w2v[4 + (r >> 2)][r & 3], pm);
        }
        int pi = __builtin_bit_cast(int, pm);
        auto rr = __builtin_amdgcn_permlane32_swap(pi, pi, false, false);
        float tot = __builtin_bit_cast(float, (int)rr[0])
                  + __builtin_bit_cast(float, (int)rr[1]);

        if (!h5)
            out[n] = xb[3] + tot + gamb2;       // residual on last input channel
    }
}

extern "C" void kernel_launch(void* const* d_in, const int* in_sizes, int n_in,
                              void* d_out, int out_size, void* d_ws, size_t ws_size,
                              hipStream_t stream) {
    const float* x   = (const float*)d_in[0];
    const float* pos = (const float*)d_in[1];
    const int*   ei  = (const int*)d_in[2];

    float* ws    = (float*)d_ws;
    int*   flags = (int*)(ws + 208100);

    prep<<<70, 256, 0, stream>>>(
        (const float*)d_in[3],  (const float*)d_in[4],  (const float*)d_in[5],
        (const float*)d_in[6],  (const float*)d_in[7],  (const float*)d_in[8],
        (const float*)d_in[9],  (const float*)d_in[10], (const float*)d_in[11],
        (const float*)d_in[12], (const float*)d_in[13], (const float*)d_in[14],
        ei, ws);

    edge_mfma<<<2048, 256, 0, stream>>>(x, pos, ei, ws, flags);

    node_mfma<<<512, 256, 0, stream>>>(x, ws, (float*)d_out);
}